// Round 21
// baseline (298.079 us; speedup 1.0000x reference)
//
#include <hip/hip_runtime.h>

#define T_ 32
#define B_ 32
#define S_ 64
#define C_ 1024
#define H_ 1024
#define NWG 64
#define HSLOT 32768  // ushorts per h ring slot / x_t slab

typedef __attribute__((ext_vector_type(8))) short bf16x8;
typedef __attribute__((ext_vector_type(4))) float f32x4;

// d_out layout (float offsets): outputs[32*32*1024], h[32*1024], c[32*1024], attn[32*32*64]
#define OUT_H   1048576
#define OUT_CC  1081344
#define OUT_AT  1114112

__device__ __forceinline__ ushort f2b(float f) {
  unsigned u = __float_as_uint(f);
  unsigned r = (u + 0x7FFFu + ((u >> 16) & 1u)) >> 16;
  return (ushort)r;
}
__device__ __forceinline__ float b2f(ushort h) {
  return __uint_as_float(((unsigned)h) << 16);
}

// ---- init: cvt inp + Wih to bf16; zero hring slot0; zero flags ----
__global__ __launch_bounds__(256) void k_init(const float* __restrict__ inp, ushort* __restrict__ inpb,
                                              const float* __restrict__ Wih, ushort* __restrict__ Wihb,
                                              ushort* __restrict__ hring, unsigned* __restrict__ flags) {
  int blk = blockIdx.x, tid = threadIdx.x;
  if (blk < 2560) {
    const float* src; ushort* dst; int base;
    if (blk < 512) { src = inp; dst = inpb; base = blk; }
    else { src = Wih; dst = Wihb; base = blk - 512; }
    size_t i = ((size_t)base * 256 + tid) * 8;
    float4 v0 = *reinterpret_cast<const float4*>(src + i);
    float4 v1 = *reinterpret_cast<const float4*>(src + i + 4);
    uint4 o;
    o.x = (unsigned)f2b(v0.x) | ((unsigned)f2b(v0.y) << 16);
    o.y = (unsigned)f2b(v0.z) | ((unsigned)f2b(v0.w) << 16);
    o.z = (unsigned)f2b(v1.x) | ((unsigned)f2b(v1.y) << 16);
    o.w = (unsigned)f2b(v1.z) | ((unsigned)f2b(v1.w) << 16);
    *reinterpret_cast<uint4*>(dst + i) = o;
  } else if (blk < 2564) {
    unsigned* hz = reinterpret_cast<unsigned*>(hring);
    int base = (blk - 2560) * 4096;
    for (int i = 0; i < 16; ++i) hz[base + i * 256 + tid] = 0u;
  } else {
    for (int i = 0; i < 8; ++i) flags[i * 256 + tid] = 0u;
  }
}

// ---- cooperative kernel: 224 WGs x 1024 threads ----
// WGs 0..63   : persistent recurrence (r8 step structure; xpT consumed via xflag gating)
// WGs 64..95  : attention (computes v itself) + outputs/attn broadcast; exit
// WGs 96..223 : x-projection producers: WG j -> t=(j-96)>>2, gate=(j-96)&3; publish xpT slab
//               [t][hid][b][gate] via byte-disjoint agent-scope stores + atomicAdd(xflag[t]); exit
__global__ __launch_bounds__(1024, 4) void k_rec(const float* __restrict__ Whh, const ushort* __restrict__ Wihb,
                                                 const ushort* __restrict__ inpb, ushort* __restrict__ hring,
                                                 const float* __restrict__ ctx,
                                                 const float* __restrict__ W1, const float* __restrict__ W2,
                                                 const float* __restrict__ bih, const float* __restrict__ bhh,
                                                 float* __restrict__ out, unsigned* __restrict__ flags,
                                                 ushort* __restrict__ xpT) {
  int tid = threadIdx.x, lane = tid & 63, w = tid >> 6;
  int wg = blockIdx.x;

  __shared__ uint4 hl4[4096];           // 64 KB staging: idx = row*128 + (c16 ^ (row&7))
  __shared__ float red[4][4][16][32];   // 32 KB K-slice partials
  __shared__ __align__(16) ushort hs[32][16];
  __shared__ float v_s[1024];
  __shared__ float sc_s[64];
  __shared__ float att_s[64];

  if (wg >= NWG + 32) {
    // ================= x-projection producer =================
    int j = wg - (NWG + 32);
    int t = j >> 2, gate = j & 3;
    // stage x_t
    {
      const uint4* s4 = reinterpret_cast<const uint4*>(inpb + (size_t)t * HSLOT);
      uint4 v0 = s4[tid], v1 = s4[tid + 1024], v2 = s4[tid + 2048], v3 = s4[tid + 3072];
      int c0 = tid, c1 = tid + 1024, c2 = tid + 2048, c3 = tid + 3072;
      hl4[(c0 >> 7) * 128 + ((c0 & 127) ^ ((c0 >> 7) & 7))] = v0;
      hl4[(c1 >> 7) * 128 + ((c1 & 127) ^ ((c1 >> 7) & 7))] = v1;
      hl4[(c2 >> 7) * 128 + ((c2 & 127) ^ ((c2 >> 7) & 7))] = v2;
      hl4[(c3 >> 7) * 128 + ((c3 & 127) ^ ((c3 >> 7) & 7))] = v3;
    }
    __syncthreads();
    int g = lane >> 4, r = lane & 15;
    f32x4 acc[2][4];
#pragma unroll
    for (int a = 0; a < 2; ++a)
#pragma unroll
      for (int b = 0; b < 4; ++b) acc[a][b] = (f32x4)(0.f);
#pragma unroll 4
    for (int kstep = 0; kstep < 32; ++kstep) {
      int c16 = kstep * 4 + g;
      bf16x8 af0 = *reinterpret_cast<const bf16x8*>(&hl4[r * 128 + (c16 ^ (r & 7))]);
      bf16x8 af1 = *reinterpret_cast<const bf16x8*>(&hl4[(16 + r) * 128 + (c16 ^ (r & 7))]);
#pragma unroll
      for (int hq = 0; hq < 4; ++hq) {
        int hid = w * 64 + hq * 16 + r;
        bf16x8 bw = *reinterpret_cast<const bf16x8*>(Wihb + (size_t)(gate * 1024 + hid) * 1024 + kstep * 32 + g * 8);
        acc[0][hq] = __builtin_amdgcn_mfma_f32_16x16x32_bf16(af0, bw, acc[0][hq], 0, 0, 0);
        acc[1][hq] = __builtin_amdgcn_mfma_f32_16x16x32_bf16(af1, bw, acc[1][hq], 0, 0, 0);
      }
    }
    __syncthreads();  // x reads done; reuse hl4 as bf16 xs[hid(1024)][b(32)]
    {
      ushort* xs = reinterpret_cast<ushort*>(hl4);
      int q = lane >> 4;
#pragma unroll
      for (int bh = 0; bh < 2; ++bh)
#pragma unroll
        for (int hq = 0; hq < 4; ++hq)
#pragma unroll
          for (int e = 0; e < 4; ++e)
            xs[(w * 64 + hq * 16 + r) * 32 + bh * 16 + q * 4 + e] = f2b(acc[bh][hq][e]);
    }
    __syncthreads();
    // publish [t][hid][b][gate]: thread owns hid = tid; 32 x 2B agent-scope stores (stride 8B)
    {
      const ushort* xs = reinterpret_cast<const ushort*>(hl4);
      ushort* dst = xpT + ((size_t)(t * 1024 + tid) * 32) * 4 + gate;
#pragma unroll
      for (int b = 0; b < 32; ++b) {
        __hip_atomic_store(dst + b * 4, xs[tid * 32 + b], __ATOMIC_RELAXED, __HIP_MEMORY_SCOPE_AGENT);
      }
    }
    asm volatile("s_waitcnt vmcnt(0)" ::: "memory");
    __syncthreads();
    if (tid == 0)
      __hip_atomic_fetch_add(&flags[1024 + t], 1u, __ATOMIC_RELAXED, __HIP_MEMORY_SCOPE_AGENT);
    return;
  }

  if (wg >= NWG) {
    // ================= attention path (batch b = wg-64) =================
    int b = wg - NWG;
    {
      float acc = 0.f;
#pragma unroll 8
      for (int a = 0; a < 128; ++a) acc += W1[a * 2048 + 1024 + tid] * W2[a];
      v_s[tid] = acc;
    }
    __syncthreads();
    {
      int s = w * 4;
#pragma unroll
      for (int si = 0; si < 4; ++si, ++s) {
        const float* xr = ctx + (size_t)(s * B_ + b) * C_;
        float acc = 0.f;
#pragma unroll
        for (int i = 0; i < 16; ++i) { int c = lane + i * 64; acc += xr[c] * v_s[c]; }
        for (int off = 32; off; off >>= 1) acc += __shfl_down(acc, off);
        if (lane == 0) sc_s[s] = acc;
      }
    }
    __syncthreads();
    if (tid < 64) {
      float val = sc_s[tid];
      float mx = val;
      for (int off = 32; off; off >>= 1) mx = fmaxf(mx, __shfl_xor(mx, off));
      float e = expf(val - mx);
      float sm = e;
      for (int off = 32; off; off >>= 1) sm += __shfl_xor(sm, off);
      att_s[tid] = e / sm;
    }
    __syncthreads();
    if (tid < 256) {
      const float4* ctx4 = reinterpret_cast<const float4*>(ctx);
      float4 a4 = {0.f, 0.f, 0.f, 0.f};
      for (int s = 0; s < 64; ++s) {
        float a = att_s[s];
        float4 x = ctx4[(size_t)(s * B_ + b) * 256 + tid];
        a4.x += a * x.x; a4.y += a * x.y; a4.z += a * x.z; a4.w += a * x.w;
      }
#pragma unroll 4
      for (int t = 0; t < T_; ++t)
        reinterpret_cast<float4*>(out + (size_t)(t * B_ + b) * C_)[tid] = a4;
    }
    if (tid < 64) {
      float av = att_s[tid];
#pragma unroll 4
      for (int t = 0; t < T_; ++t) out[OUT_AT + (t * B_ + b) * 64 + tid] = av;
    }
    return;
  }

  // ================= recurrence path (r8 step structure) =================
  int q = w & 3, ks = w >> 2;
  int g = lane >> 4, r = lane & 15;
  int hidx0 = wg * 16 + q * 4;
  int kbase = ks * 256;
  int j = (r >> 2) * 1024 + hidx0 + (r & 3);
  // W_hh fragments: f32 load + in-register bf16 pack
  bf16x8 ah[8];
  {
    const float* ap = Whh + (size_t)j * 1024 + kbase + g * 8;
#pragma unroll
    for (int kk = 0; kk < 8; ++kk) {
      float4 f0 = *reinterpret_cast<const float4*>(ap + kk * 32);
      float4 f1 = *reinterpret_cast<const float4*>(ap + kk * 32 + 4);
      bf16x8 t8;
      t8[0] = (short)f2b(f0.x); t8[1] = (short)f2b(f0.y);
      t8[2] = (short)f2b(f0.z); t8[3] = (short)f2b(f0.w);
      t8[4] = (short)f2b(f1.x); t8[5] = (short)f2b(f1.y);
      t8[6] = (short)f2b(f1.z); t8[7] = (short)f2b(f1.w);
      ah[kk] = t8;
    }
  }
  float c_reg = 0.f;
  int eb = tid & 31, hl = (tid >> 5) & 3, qq = tid >> 7;  // epilogue cell (tid<512)
  int ehidx = wg * 16 + qq * 4 + hl;
  float bs_i = 0.f, bs_f = 0.f, bs_g = 0.f, bs_o = 0.f;
  if (tid < 512) {
    bs_i = bih[ehidx] + bhh[ehidx];
    bs_f = bih[1024 + ehidx] + bhh[1024 + ehidx];
    bs_g = bih[2048 + ehidx] + bhh[2048 + ehidx];
    bs_o = bih[3072 + ehidx] + bhh[3072 + ehidx];
  }
  int cb = ks * 32 + g;

#pragma unroll 1
  for (int t = 0; t < T_; ++t) {
    // ---- poll (w0): h flags (t>0) + xpT slab readiness for step t ----
    if (w == 0) {
      if (t > 0) {
        for (;;) {
          unsigned vfl = __hip_atomic_load(&flags[lane * 16], __ATOMIC_RELAXED, __HIP_MEMORY_SCOPE_AGENT);
          if (__all((int)(vfl >= (unsigned)t))) break;
          __builtin_amdgcn_s_sleep(1);
        }
      }
      for (;;) {
        unsigned xf = __hip_atomic_load(&flags[1024 + t], __ATOMIC_RELAXED, __HIP_MEMORY_SCOPE_AGENT);
        if (__all((int)(xf >= 4u))) break;
        __builtin_amdgcn_s_sleep(1);
      }
    }
    __syncthreads();  // S1
    // ---- stage h slot t (FIRST vmem in FIFO this step) ----
    {
      const uint4* s4 = reinterpret_cast<const uint4*>(hring + (size_t)t * HSLOT);
      uint4 v0 = s4[tid], v1 = s4[tid + 1024], v2 = s4[tid + 2048], v3 = s4[tid + 3072];
      int c0 = tid, c1 = tid + 1024, c2 = tid + 2048, c3 = tid + 3072;
      hl4[(c0 >> 7) * 128 + ((c0 & 127) ^ ((c0 >> 7) & 7))] = v0;
      hl4[(c1 >> 7) * 128 + ((c1 & 127) ^ ((c1 >> 7) & 7))] = v1;
      hl4[(c2 >> 7) * 128 + ((c2 & 127) ^ ((c2 >> 7) & 7))] = v2;
      hl4[(c3 >> 7) * 128 + ((c3 & 127) ^ ((c3 >> 7) & 7))] = v3;
    }
    __syncthreads();  // S2
    // issue xpT load NOW: one ushort4 (gates i,f,g,o packed); hides under MFMA + red + S3
    ushort4 xv4 = {0, 0, 0, 0};
    if (tid < 512)
      xv4 = *reinterpret_cast<const ushort4*>(xpT + ((size_t)(t * 1024 + ehidx) * 32 + eb) * 4);
    f32x4 acc0 = (f32x4)(0.f), acc1 = (f32x4)(0.f);
#pragma unroll
    for (int kk = 0; kk < 8; ++kk) {
      int c16 = cb + kk * 4;
      bf16x8 b0 = *reinterpret_cast<const bf16x8*>(&hl4[r * 128 + (c16 ^ (r & 7))]);
      bf16x8 b1 = *reinterpret_cast<const bf16x8*>(&hl4[(r + 16) * 128 + (c16 ^ (r & 7))]);
      acc0 = __builtin_amdgcn_mfma_f32_16x16x32_bf16(ah[kk], b0, acc0, 0, 0, 0);
      acc1 = __builtin_amdgcn_mfma_f32_16x16x32_bf16(ah[kk], b1, acc1, 0, 0, 0);
    }
#pragma unroll
    for (int e = 0; e < 4; ++e) {
      red[q][ks][g * 4 + e][r] = acc0[e];
      red[q][ks][g * 4 + e][r + 16] = acc1[e];
    }
    __syncthreads();  // S3
    if (tid < 512) {
      float ig = red[qq][0][0 + hl][eb]  + red[qq][1][0 + hl][eb]  + red[qq][2][0 + hl][eb]  + red[qq][3][0 + hl][eb]  + b2f(xv4.x) + bs_i;
      float fg = red[qq][0][4 + hl][eb]  + red[qq][1][4 + hl][eb]  + red[qq][2][4 + hl][eb]  + red[qq][3][4 + hl][eb]  + b2f(xv4.y) + bs_f;
      float gg = red[qq][0][8 + hl][eb]  + red[qq][1][8 + hl][eb]  + red[qq][2][8 + hl][eb]  + red[qq][3][8 + hl][eb]  + b2f(xv4.z) + bs_g;
      float og = red[qq][0][12 + hl][eb] + red[qq][1][12 + hl][eb] + red[qq][2][12 + hl][eb] + red[qq][3][12 + hl][eb] + b2f(xv4.w) + bs_o;
      float si = 1.f / (1.f + __expf(-ig));
      float sf = 1.f / (1.f + __expf(-fg));
      float so = 1.f / (1.f + __expf(-og));
      float c_new = sf * c_reg + si * tanhf(gg);
      float h_new = so * tanhf(c_new);
      c_reg = c_new;
      hs[eb][qq * 4 + hl] = f2b(h_new);
      if (t == T_ - 1) {
        out[OUT_H + eb * 1024 + ehidx] = h_new;
        out[OUT_CC + eb * 1024 + ehidx] = c_new;
      }
    }
    __syncthreads();  // S4: hs ready
    if (t != T_ - 1 && w == 0) {
      ushort* hout = hring + (size_t)(t + 1) * HSLOT;
      int b = lane >> 1, half = lane & 1;
      uint4 vv = *reinterpret_cast<const uint4*>(&hs[b][half * 8]);
      unsigned* hp = reinterpret_cast<unsigned*>(hout) + b * 512 + wg * 8 + half * 4;
      __hip_atomic_store(hp + 0, vv.x, __ATOMIC_RELAXED, __HIP_MEMORY_SCOPE_AGENT);
      __hip_atomic_store(hp + 1, vv.y, __ATOMIC_RELAXED, __HIP_MEMORY_SCOPE_AGENT);
      __hip_atomic_store(hp + 2, vv.z, __ATOMIC_RELAXED, __HIP_MEMORY_SCOPE_AGENT);
      __hip_atomic_store(hp + 3, vv.w, __ATOMIC_RELAXED, __HIP_MEMORY_SCOPE_AGENT);
      asm volatile("s_waitcnt vmcnt(0)" ::: "memory");
      if (lane == 0)
        __hip_atomic_store(&flags[wg * 16], (unsigned)(t + 1), __ATOMIC_RELAXED, __HIP_MEMORY_SCOPE_AGENT);
    }
  }
}

extern "C" void kernel_launch(void* const* d_in, const int* in_sizes, int n_in,
                              void* d_out, int out_size, void* d_ws, size_t ws_size,
                              hipStream_t stream) {
  const float* inp = (const float*)d_in[0];
  const float* ctx = (const float*)d_in[1];
  const float* Wih = (const float*)d_in[2];
  const float* Whh = (const float*)d_in[3];
  const float* bih = (const float*)d_in[4];
  const float* bhh = (const float*)d_in[5];
  const float* W1  = (const float*)d_in[6];
  const float* W2  = (const float*)d_in[8];
  float* out = (float*)d_out;
  char* wsb = (char*)d_ws;

  unsigned* flags = (unsigned*)(wsb + 0);      // 8 KB (h-flags @ i*16, xflags @ 1024+t)
  ushort* inpb  = (ushort*)(wsb + 8192);       // 2 MB
  ushort* Wihb  = (ushort*)(wsb + 2105344);    // 8 MB
  ushort* xpT   = (ushort*)(wsb + 10493952);   // 8 MB [t][hid][b][gate] bf16
  ushort* hring = (ushort*)(wsb + 18882560);   // 33 slots x 64 KB = 2112 KB

  hipLaunchKernelGGL(k_init, dim3(2565), dim3(256), 0, stream, inp, inpb, Wih, Wihb, hring, flags);

  const float* Whh_c = Whh;
  const ushort* Wihb_c = Wihb;
  const ushort* inpb_c = inpb;
  const float* ctx_c = ctx;
  const float* W1_c = W1;
  const float* W2_c = W2;
  const float* bih_c = bih;
  const float* bhh_c = bhh;
  void* kargs[12];
  kargs[0] = (void*)&Whh_c;
  kargs[1] = (void*)&Wihb_c;
  kargs[2] = (void*)&inpb_c;
  kargs[3] = (void*)&hring;
  kargs[4] = (void*)&ctx_c;
  kargs[5] = (void*)&W1_c;
  kargs[6] = (void*)&W2_c;
  kargs[7] = (void*)&bih_c;
  kargs[8] = (void*)&bhh_c;
  kargs[9] = (void*)&out;
  kargs[10] = (void*)&flags;
  kargs[11] = (void*)&xpT;
  hipLaunchCooperativeKernel((const void*)k_rec, dim3(NWG + 32 + 128), dim3(1024), kargs, 0, stream);
}

// Round 22
// 249.681 us; speedup vs baseline: 1.1938x; 1.1938x over previous
//
#include <hip/hip_runtime.h>

#define T_ 32
#define B_ 32
#define S_ 64
#define C_ 1024
#define H_ 1024
#define NWG 64
#define HSLOT 32768  // ushorts per h ring slot / per x_t slab (32 x 1024)

typedef __attribute__((ext_vector_type(8))) short bf16x8;
typedef __attribute__((ext_vector_type(4))) float f32x4;

// d_out layout (float offsets): outputs[32*32*1024], h[32*1024], c[32*1024], attn[32*32*64]
#define OUT_H   1048576
#define OUT_CC  1081344
#define OUT_AT  1114112

__device__ __forceinline__ ushort f2b(float f) {
  unsigned u = __float_as_uint(f);
  unsigned r = (u + 0x7FFFu + ((u >> 16) & 1u)) >> 16;
  return (ushort)r;
}
__device__ __forceinline__ float b2f(ushort h) {
  return __uint_as_float(((unsigned)h) << 16);
}

// ---------------- init: cvt inp/Wih/Whh to bf16, v = W2@W1_x, bias, zero h slot0, zero flags ----------------
__global__ __launch_bounds__(256) void k_init(const float* __restrict__ inp, ushort* __restrict__ inpb,
                                              const float* __restrict__ Wih, ushort* __restrict__ Wihb,
                                              const float* __restrict__ Whh, ushort* __restrict__ Whhb,
                                              const float* __restrict__ W1, const float* __restrict__ W2,
                                              const float* __restrict__ bih, const float* __restrict__ bhh,
                                              float* __restrict__ v, float* __restrict__ bias,
                                              ushort* __restrict__ hring, unsigned* __restrict__ flags) {
  int blk = blockIdx.x, tid = threadIdx.x;
  if (blk < 4608) {
    const float* src; ushort* dst; int base;
    if (blk < 512) { src = inp; dst = inpb; base = blk; }
    else if (blk < 2560) { src = Wih; dst = Wihb; base = blk - 512; }
    else { src = Whh; dst = Whhb; base = blk - 2560; }
    size_t i = ((size_t)base * 256 + tid) * 8;
    float4 v0 = *reinterpret_cast<const float4*>(src + i);
    float4 v1 = *reinterpret_cast<const float4*>(src + i + 4);
    uint4 o;
    o.x = (unsigned)f2b(v0.x) | ((unsigned)f2b(v0.y) << 16);
    o.y = (unsigned)f2b(v0.z) | ((unsigned)f2b(v0.w) << 16);
    o.z = (unsigned)f2b(v1.x) | ((unsigned)f2b(v1.y) << 16);
    o.w = (unsigned)f2b(v1.z) | ((unsigned)f2b(v1.w) << 16);
    *reinterpret_cast<uint4*>(dst + i) = o;
  } else if (blk < 4612) {
    int c = (blk - 4608) * 256 + tid;
    float acc = 0.f;
#pragma unroll 8
    for (int a = 0; a < 128; ++a) acc += W1[a * 2048 + 1024 + c] * W2[a];
    v[c] = acc;
  } else if (blk < 4628) {
    int jj = (blk - 4612) * 256 + tid;
    bias[jj] = bih[jj] + bhh[jj];
  } else if (blk < 4632) {
    unsigned* hz = reinterpret_cast<unsigned*>(hring);
    int base = (blk - 4628) * 4096;
    for (int i = 0; i < 16; ++i) hz[base + i * 256 + tid] = 0u;
  } else {
    for (int i = 0; i < 4; ++i) flags[i * 256 + tid] = 0u;
  }
}

// ---------------- cooperative kernel: 96 WGs x 1024 threads ----------------
// WGs 0..63: persistent recurrence + fused x-projection (r15 structure + T14 x-prefetch +
//            deferred publish drain: w0 issues sc1 stores at step end; vmcnt+flag ride
//            under the next step's ds_write/S1/X-MFMA window).
// WGs 64..95: attention (time-invariant) + outputs/attn broadcast on idle CUs; exit.
__global__ __launch_bounds__(1024, 4) void k_rec(const ushort* __restrict__ Whhb, const ushort* __restrict__ Wihb,
                                                 const ushort* __restrict__ inpb, ushort* __restrict__ hring,
                                                 const float* __restrict__ ctx, const float* __restrict__ v,
                                                 const float* __restrict__ bias,
                                                 float* __restrict__ out, unsigned* __restrict__ flags) {
  int tid = threadIdx.x, lane = tid & 63, w = tid >> 6;
  int wg = blockIdx.x;

  __shared__ uint4 hl4[4096];           // 64 KB staging (x_t, then h): idx = row*128 + (c16 ^ (row&7))
  __shared__ float red[4][4][16][32];   // 32 KB K-slice partials
  __shared__ __align__(16) ushort hs[32][16];
  __shared__ float v_s[1024];           // attention path
  __shared__ float sc_s[64];
  __shared__ float att_s[64];

  if (wg >= NWG) {
    // ================= attention path (1 batch per WG) =================
    int b = wg - NWG;
    v_s[tid] = v[tid];
    __syncthreads();
    {
      int s = w * 4;
#pragma unroll
      for (int si = 0; si < 4; ++si, ++s) {
        const float* xr = ctx + (size_t)(s * B_ + b) * C_;
        float acc = 0.f;
#pragma unroll
        for (int i = 0; i < 16; ++i) { int c = lane + i * 64; acc += xr[c] * v_s[c]; }
        for (int off = 32; off; off >>= 1) acc += __shfl_down(acc, off);
        if (lane == 0) sc_s[s] = acc;
      }
    }
    __syncthreads();
    if (tid < 64) {
      float val = sc_s[tid];
      float mx = val;
      for (int off = 32; off; off >>= 1) mx = fmaxf(mx, __shfl_xor(mx, off));
      float e = expf(val - mx);
      float sm = e;
      for (int off = 32; off; off >>= 1) sm += __shfl_xor(sm, off);
      att_s[tid] = e / sm;
    }
    __syncthreads();
    if (tid < 256) {
      const float4* ctx4 = reinterpret_cast<const float4*>(ctx);
      float4 a4 = {0.f, 0.f, 0.f, 0.f};
      for (int s = 0; s < 64; ++s) {
        float a = att_s[s];
        float4 x = ctx4[(size_t)(s * B_ + b) * 256 + tid];
        a4.x += a * x.x; a4.y += a * x.y; a4.z += a * x.z; a4.w += a * x.w;
      }
#pragma unroll 4
      for (int t = 0; t < T_; ++t)
        reinterpret_cast<float4*>(out + (size_t)(t * B_ + b) * C_)[tid] = a4;
    }
    if (tid < 64) {
      float av = att_s[tid];
#pragma unroll 4
      for (int t = 0; t < T_; ++t) out[OUT_AT + (t * B_ + b) * 64 + tid] = av;
    }
    return;
  }

  // ================= recurrence path =================
  int q = w & 3, ks = w >> 2;
  int g = lane >> 4, r = lane & 15;
  int hidx0 = wg * 16 + q * 4;
  int kbase = ks * 256;
  int j = (r >> 2) * 1024 + hidx0 + (r & 3);
  bf16x8 ah[8], ax[8];
  {
    const ushort* ap = Whhb + (size_t)j * 1024 + kbase + g * 8;
    const ushort* axp = Wihb + (size_t)j * 1024 + kbase + g * 8;
#pragma unroll
    for (int kk = 0; kk < 8; ++kk) {
      ah[kk] = *reinterpret_cast<const bf16x8*>(ap + kk * 32);
      ax[kk] = *reinterpret_cast<const bf16x8*>(axp + kk * 32);
    }
  }
  float c_reg = 0.f;
  int eb = tid & 31, hl = (tid >> 5) & 3, qq = tid >> 7;  // epilogue cell (tid<512)
  int ehidx = wg * 16 + qq * 4 + hl;
  float bs_i = 0.f, bs_f = 0.f, bs_g = 0.f, bs_o = 0.f;
  if (tid < 512) {
    bs_i = bias[ehidx];
    bs_f = bias[1024 + ehidx];
    bs_g = bias[2048 + ehidx];
    bs_o = bias[3072 + ehidx];
  }
  int cb = ks * 32 + g;
  int c0 = tid, c1 = tid + 1024, c2 = tid + 2048, c3 = tid + 3072;
  int sw0 = (c0 >> 7) * 128 + ((c0 & 127) ^ ((c0 >> 7) & 7));
  int sw1 = (c1 >> 7) * 128 + ((c1 & 127) ^ ((c1 >> 7) & 7));
  int sw2 = (c2 >> 7) * 128 + ((c2 & 127) ^ ((c2 >> 7) & 7));
  int sw3 = (c3 >> 7) * 128 + ((c3 & 127) ^ ((c3 >> 7) & 7));

  // T14: prefetch x_0 into registers
  uint4 xr0, xr1, xr2, xr3;
  {
    const uint4* s4 = reinterpret_cast<const uint4*>(inpb);
    xr0 = s4[c0]; xr1 = s4[c1]; xr2 = s4[c2]; xr3 = s4[c3];
  }

#pragma unroll 1
  for (int t = 0; t < T_; ++t) {
    // ---- phase X: ds_write prefetched x_t (no global wait), then X-MFMA ----
    hl4[sw0] = xr0; hl4[sw1] = xr1; hl4[sw2] = xr2; hl4[sw3] = xr3;
    __syncthreads();  // S1
    f32x4 acc0 = (f32x4)(0.f), acc1 = (f32x4)(0.f);
#pragma unroll
    for (int kk = 0; kk < 8; ++kk) {
      int c16 = cb + kk * 4;
      bf16x8 b0 = *reinterpret_cast<const bf16x8*>(&hl4[r * 128 + (c16 ^ (r & 7))]);
      bf16x8 b1 = *reinterpret_cast<const bf16x8*>(&hl4[(r + 16) * 128 + (c16 ^ (r & 7))]);
      acc0 = __builtin_amdgcn_mfma_f32_16x16x32_bf16(ax[kk], b0, acc0, 0, 0, 0);
      acc1 = __builtin_amdgcn_mfma_f32_16x16x32_bf16(ax[kk], b1, acc1, 0, 0, 0);
    }
    // ---- w0: drain prev-step publish (stores issued at step end), set flag, poll ----
    if (t > 0 && w == 0) {
      asm volatile("s_waitcnt vmcnt(0)" ::: "memory");  // slot-t sc1 stores durable at IF
      if (lane == 0)
        __hip_atomic_store(&flags[wg * 16], (unsigned)t, __ATOMIC_RELAXED, __HIP_MEMORY_SCOPE_AGENT);
      for (;;) {
        unsigned vfl = __hip_atomic_load(&flags[lane * 16], __ATOMIC_RELAXED, __HIP_MEMORY_SCOPE_AGENT);
        if (__all((int)(vfl >= (unsigned)t))) break;
        __builtin_amdgcn_s_sleep(1);
      }
    }
    __syncthreads();  // S2: gates h restage; all waves done reading x from hl4
    // ---- phase H: stage h slot t ----
    {
      const uint4* s4 = reinterpret_cast<const uint4*>(hring + (size_t)t * HSLOT);
      uint4 v0 = s4[c0], v1 = s4[c1], v2 = s4[c2], v3 = s4[c3];
      hl4[sw0] = v0; hl4[sw1] = v1; hl4[sw2] = v2; hl4[sw3] = v3;
    }
    // T14: prefetch x_{t+1} into registers (L2-resident; retires during H-MFMA/red)
    if (t < T_ - 1) {
      const uint4* s4 = reinterpret_cast<const uint4*>(inpb + (size_t)(t + 1) * HSLOT);
      xr0 = s4[c0]; xr1 = s4[c1]; xr2 = s4[c2]; xr3 = s4[c3];
    }
    __syncthreads();  // S3
#pragma unroll
    for (int kk = 0; kk < 8; ++kk) {
      int c16 = cb + kk * 4;
      bf16x8 b0 = *reinterpret_cast<const bf16x8*>(&hl4[r * 128 + (c16 ^ (r & 7))]);
      bf16x8 b1 = *reinterpret_cast<const bf16x8*>(&hl4[(r + 16) * 128 + (c16 ^ (r & 7))]);
      acc0 = __builtin_amdgcn_mfma_f32_16x16x32_bf16(ah[kk], b0, acc0, 0, 0, 0);
      acc1 = __builtin_amdgcn_mfma_f32_16x16x32_bf16(ah[kk], b1, acc1, 0, 0, 0);
    }
#pragma unroll
    for (int e = 0; e < 4; ++e) {
      red[q][ks][g * 4 + e][r] = acc0[e];
      red[q][ks][g * 4 + e][r + 16] = acc1[e];
    }
    __syncthreads();  // S4
    if (tid < 512) {
      float ig = red[qq][0][0 + hl][eb]  + red[qq][1][0 + hl][eb]  + red[qq][2][0 + hl][eb]  + red[qq][3][0 + hl][eb]  + bs_i;
      float fg = red[qq][0][4 + hl][eb]  + red[qq][1][4 + hl][eb]  + red[qq][2][4 + hl][eb]  + red[qq][3][4 + hl][eb]  + bs_f;
      float gg = red[qq][0][8 + hl][eb]  + red[qq][1][8 + hl][eb]  + red[qq][2][8 + hl][eb]  + red[qq][3][8 + hl][eb]  + bs_g;
      float og = red[qq][0][12 + hl][eb] + red[qq][1][12 + hl][eb] + red[qq][2][12 + hl][eb] + red[qq][3][12 + hl][eb] + bs_o;
      float si = 1.f / (1.f + __expf(-ig));
      float sf = 1.f / (1.f + __expf(-fg));
      float so = 1.f / (1.f + __expf(-og));
      float c_new = sf * c_reg + si * tanhf(gg);
      float h_new = so * tanhf(c_new);
      c_reg = c_new;
      hs[eb][qq * 4 + hl] = f2b(h_new);
      if (t == T_ - 1) {
        out[OUT_H + eb * 1024 + ehidx] = h_new;
        out[OUT_CC + eb * 1024 + ehidx] = c_new;
      }
    }
    __syncthreads();  // S5: hs ready
    if (t != T_ - 1 && w == 0) {
      // ISSUE publish sc1 stores only; vmcnt+flag deferred to next step's w0 block
      ushort* hout = hring + (size_t)(t + 1) * HSLOT;
      int b = lane >> 1, half = lane & 1;
      uint4 vv = *reinterpret_cast<const uint4*>(&hs[b][half * 8]);
      unsigned* hp = reinterpret_cast<unsigned*>(hout) + b * 512 + wg * 8 + half * 4;
      __hip_atomic_store(hp + 0, vv.x, __ATOMIC_RELAXED, __HIP_MEMORY_SCOPE_AGENT);
      __hip_atomic_store(hp + 1, vv.y, __ATOMIC_RELAXED, __HIP_MEMORY_SCOPE_AGENT);
      __hip_atomic_store(hp + 2, vv.z, __ATOMIC_RELAXED, __HIP_MEMORY_SCOPE_AGENT);
      __hip_atomic_store(hp + 3, vv.w, __ATOMIC_RELAXED, __HIP_MEMORY_SCOPE_AGENT);
    }
  }
}

extern "C" void kernel_launch(void* const* d_in, const int* in_sizes, int n_in,
                              void* d_out, int out_size, void* d_ws, size_t ws_size,
                              hipStream_t stream) {
  const float* inp = (const float*)d_in[0];
  const float* ctx = (const float*)d_in[1];
  const float* Wih = (const float*)d_in[2];
  const float* Whh = (const float*)d_in[3];
  const float* bih = (const float*)d_in[4];
  const float* bhh = (const float*)d_in[5];
  const float* W1  = (const float*)d_in[6];
  const float* W2  = (const float*)d_in[8];
  float* out = (float*)d_out;
  char* wsb = (char*)d_ws;

  float* v     = (float*)(wsb + 0);          // 4 KB
  float* bias  = (float*)(wsb + 4096);       // 16 KB
  ushort* hring = (ushort*)(wsb + 32768);    // 33 slots x 64 KB = 2112 KB
  ushort* inpb = (ushort*)(wsb + 2195456);   // 2 MB
  ushort* Wihb = (ushort*)(wsb + 4292608);   // 8 MB
  ushort* Whhb = (ushort*)(wsb + 12681216);  // 8 MB
  unsigned* flags = (unsigned*)(wsb + 21069824); // 4 KB (64 flags, 64B apart)

  hipLaunchKernelGGL(k_init, dim3(4633), dim3(256), 0, stream,
                     inp, inpb, Wih, Wihb, Whh, Whhb, W1, W2, bih, bhh, v, bias, hring, flags);

  const ushort* Whhb_c = Whhb;
  const ushort* Wihb_c = Wihb;
  const ushort* inpb_c = inpb;
  const float* ctx_c = ctx;
  const float* v_c = v;
  const float* bias_c = bias;
  void* kargs[9];
  kargs[0] = (void*)&Whhb_c;
  kargs[1] = (void*)&Wihb_c;
  kargs[2] = (void*)&inpb_c;
  kargs[3] = (void*)&hring;
  kargs[4] = (void*)&ctx_c;
  kargs[5] = (void*)&v_c;
  kargs[6] = (void*)&bias_c;
  kargs[7] = (void*)&out;
  kargs[8] = (void*)&flags;
  hipLaunchCooperativeKernel((const void*)k_rec, dim3(NWG + 32), dim3(1024), kargs, 0, stream);
}

// Round 23
// 213.275 us; speedup vs baseline: 1.3976x; 1.1707x over previous
//
#include <hip/hip_runtime.h>

#define T_ 32
#define B_ 32
#define S_ 64
#define C_ 1024
#define H_ 1024
#define NWG 64
#define HSLOT 32768  // ushorts per h ring slot / per x_t slab (32 x 1024)

typedef __attribute__((ext_vector_type(8))) short bf16x8;
typedef __attribute__((ext_vector_type(4))) float f32x4;

// d_out layout (float offsets): outputs[32*32*1024], h[32*1024], c[32*1024], attn[32*32*64]
#define OUT_H   1048576
#define OUT_CC  1081344
#define OUT_AT  1114112

__device__ __forceinline__ ushort f2b(float f) {
  unsigned u = __float_as_uint(f);
  unsigned r = (u + 0x7FFFu + ((u >> 16) & 1u)) >> 16;
  return (ushort)r;
}
__device__ __forceinline__ float b2f(ushort h) {
  return __uint_as_float(((unsigned)h) << 16);
}

// ---------------- init: cvt inp to bf16, v = W2@W1_x, bias, zero h slot0, zero flags ----------------
__global__ __launch_bounds__(256) void k_init(const float* __restrict__ inp, ushort* __restrict__ inpb,
                                              const float* __restrict__ W1, const float* __restrict__ W2,
                                              const float* __restrict__ bih, const float* __restrict__ bhh,
                                              float* __restrict__ v, float* __restrict__ bias,
                                              ushort* __restrict__ hring, unsigned* __restrict__ flags) {
  int blk = blockIdx.x, tid = threadIdx.x;
  if (blk < 512) {
    size_t i = ((size_t)blk * 256 + tid) * 8;
    float4 v0 = *reinterpret_cast<const float4*>(inp + i);
    float4 v1 = *reinterpret_cast<const float4*>(inp + i + 4);
    uint4 o;
    o.x = (unsigned)f2b(v0.x) | ((unsigned)f2b(v0.y) << 16);
    o.y = (unsigned)f2b(v0.z) | ((unsigned)f2b(v0.w) << 16);
    o.z = (unsigned)f2b(v1.x) | ((unsigned)f2b(v1.y) << 16);
    o.w = (unsigned)f2b(v1.z) | ((unsigned)f2b(v1.w) << 16);
    *reinterpret_cast<uint4*>(inpb + i) = o;
  } else if (blk < 516) {
    int c = (blk - 512) * 256 + tid;
    float acc = 0.f;
#pragma unroll 8
    for (int a = 0; a < 128; ++a) acc += W1[a * 2048 + 1024 + c] * W2[a];
    v[c] = acc;
  } else if (blk < 532) {
    int jj = (blk - 516) * 256 + tid;
    bias[jj] = bih[jj] + bhh[jj];
  } else if (blk < 536) {
    unsigned* hz = reinterpret_cast<unsigned*>(hring);
    int base = (blk - 532) * 4096;
    for (int i = 0; i < 16; ++i) hz[base + i * 256 + tid] = 0u;
  } else {
    for (int i = 0; i < 4; ++i) flags[i * 256 + tid] = 0u;
  }
}

// ---------------- cooperative kernel: 96 WGs x 1024 threads (r15 structure) ----------------
// WGs 0..63: persistent recurrence + fused x-projection. W fragments loaded from f32
//            inputs with in-register bf16 pack (no weight cvt pass, no bf16 W buffers).
// WGs 64..95: attention (time-invariant) + outputs/attn broadcast on idle CUs; exit.
__global__ __launch_bounds__(1024, 4) void k_rec(const float* __restrict__ Whh, const float* __restrict__ Wih,
                                                 const ushort* __restrict__ inpb, ushort* __restrict__ hring,
                                                 const float* __restrict__ ctx, const float* __restrict__ v,
                                                 const float* __restrict__ bias,
                                                 float* __restrict__ out, unsigned* __restrict__ flags) {
  int tid = threadIdx.x, lane = tid & 63, w = tid >> 6;
  int wg = blockIdx.x;

  __shared__ uint4 hl4[4096];           // 64 KB staging (x_t, then h): idx = row*128 + (c16 ^ (row&7))
  __shared__ float red[4][4][16][32];   // 32 KB K-slice partials
  __shared__ __align__(16) ushort hs[32][16];
  __shared__ float v_s[1024];           // attention path
  __shared__ float sc_s[64];
  __shared__ float att_s[64];

  if (wg >= NWG) {
    // ================= attention path (1 batch per WG; barriers hit by all 1024 threads) =================
    int b = wg - NWG;
    v_s[tid] = v[tid];
    __syncthreads();
    {
      int s = w * 4;
#pragma unroll
      for (int si = 0; si < 4; ++si, ++s) {
        const float* xr = ctx + (size_t)(s * B_ + b) * C_;
        float acc = 0.f;
#pragma unroll
        for (int i = 0; i < 16; ++i) { int c = lane + i * 64; acc += xr[c] * v_s[c]; }
        for (int off = 32; off; off >>= 1) acc += __shfl_down(acc, off);
        if (lane == 0) sc_s[s] = acc;
      }
    }
    __syncthreads();
    if (tid < 64) {
      float val = sc_s[tid];
      float mx = val;
      for (int off = 32; off; off >>= 1) mx = fmaxf(mx, __shfl_xor(mx, off));
      float e = expf(val - mx);
      float sm = e;
      for (int off = 32; off; off >>= 1) sm += __shfl_xor(sm, off);
      att_s[tid] = e / sm;
    }
    __syncthreads();
    if (tid < 256) {
      const float4* ctx4 = reinterpret_cast<const float4*>(ctx);
      float4 a4 = {0.f, 0.f, 0.f, 0.f};
      for (int s = 0; s < 64; ++s) {
        float a = att_s[s];
        float4 x = ctx4[(size_t)(s * B_ + b) * 256 + tid];
        a4.x += a * x.x; a4.y += a * x.y; a4.z += a * x.z; a4.w += a * x.w;
      }
#pragma unroll 4
      for (int t = 0; t < T_; ++t)
        reinterpret_cast<float4*>(out + (size_t)(t * B_ + b) * C_)[tid] = a4;
    }
    if (tid < 64) {
      float av = att_s[tid];
#pragma unroll 4
      for (int t = 0; t < T_; ++t) out[OUT_AT + (t * B_ + b) * 64 + tid] = av;
    }
    return;
  }

  // ================= recurrence path (r15 structure; W frags f32->bf16 in-register) =================
  int q = w & 3, ks = w >> 2;
  int g = lane >> 4, r = lane & 15;
  int hidx0 = wg * 16 + q * 4;
  int kbase = ks * 256;
  int j = (r >> 2) * 1024 + hidx0 + (r & 3);
  bf16x8 ah[8], ax[8];
  {
    const float* ap = Whh + (size_t)j * 1024 + kbase + g * 8;
    const float* axp = Wih + (size_t)j * 1024 + kbase + g * 8;
#pragma unroll
    for (int kk = 0; kk < 8; ++kk) {
      float4 f0 = *reinterpret_cast<const float4*>(ap + kk * 32);
      float4 f1 = *reinterpret_cast<const float4*>(ap + kk * 32 + 4);
      bf16x8 t8;
      t8[0] = (short)f2b(f0.x); t8[1] = (short)f2b(f0.y);
      t8[2] = (short)f2b(f0.z); t8[3] = (short)f2b(f0.w);
      t8[4] = (short)f2b(f1.x); t8[5] = (short)f2b(f1.y);
      t8[6] = (short)f2b(f1.z); t8[7] = (short)f2b(f1.w);
      ah[kk] = t8;
      float4 g0 = *reinterpret_cast<const float4*>(axp + kk * 32);
      float4 g1 = *reinterpret_cast<const float4*>(axp + kk * 32 + 4);
      bf16x8 u8;
      u8[0] = (short)f2b(g0.x); u8[1] = (short)f2b(g0.y);
      u8[2] = (short)f2b(g0.z); u8[3] = (short)f2b(g0.w);
      u8[4] = (short)f2b(g1.x); u8[5] = (short)f2b(g1.y);
      u8[6] = (short)f2b(g1.z); u8[7] = (short)f2b(g1.w);
      ax[kk] = u8;
    }
  }
  float c_reg = 0.f;
  int eb = tid & 31, hl = (tid >> 5) & 3, qq = tid >> 7;  // epilogue cell (tid<512)
  int ehidx = wg * 16 + qq * 4 + hl;
  float bs_i = 0.f, bs_f = 0.f, bs_g = 0.f, bs_o = 0.f;
  if (tid < 512) {
    bs_i = bias[ehidx];
    bs_f = bias[1024 + ehidx];
    bs_g = bias[2048 + ehidx];
    bs_o = bias[3072 + ehidx];
  }
  int cb = ks * 32 + g;

#pragma unroll 1
  for (int t = 0; t < T_; ++t) {
    // ---- phase X: stage x_t (no dependency) and accumulate W_ih @ x_t ----
    {
      const uint4* s4 = reinterpret_cast<const uint4*>(inpb + (size_t)t * HSLOT);
      uint4 v0 = s4[tid], v1 = s4[tid + 1024], v2 = s4[tid + 2048], v3 = s4[tid + 3072];
      int c0 = tid, c1 = tid + 1024, c2 = tid + 2048, c3 = tid + 3072;
      hl4[(c0 >> 7) * 128 + ((c0 & 127) ^ ((c0 >> 7) & 7))] = v0;
      hl4[(c1 >> 7) * 128 + ((c1 & 127) ^ ((c1 >> 7) & 7))] = v1;
      hl4[(c2 >> 7) * 128 + ((c2 & 127) ^ ((c2 >> 7) & 7))] = v2;
      hl4[(c3 >> 7) * 128 + ((c3 & 127) ^ ((c3 >> 7) & 7))] = v3;
    }
    __syncthreads();
    f32x4 acc0 = (f32x4)(0.f), acc1 = (f32x4)(0.f);
#pragma unroll
    for (int kk = 0; kk < 8; ++kk) {
      int c16 = cb + kk * 4;
      bf16x8 b0 = *reinterpret_cast<const bf16x8*>(&hl4[r * 128 + (c16 ^ (r & 7))]);
      bf16x8 b1 = *reinterpret_cast<const bf16x8*>(&hl4[(r + 16) * 128 + (c16 ^ (r & 7))]);
      acc0 = __builtin_amdgcn_mfma_f32_16x16x32_bf16(ax[kk], b0, acc0, 0, 0, 0);
      acc1 = __builtin_amdgcn_mfma_f32_16x16x32_bf16(ax[kk], b1, acc1, 0, 0, 0);
    }
    // ---- poll: single wave, all 64 producer flags, one 64-lane bypass load ----
    if (t > 0 && w == 0) {
      for (;;) {
        unsigned vfl = __hip_atomic_load(&flags[lane * 16], __ATOMIC_RELAXED, __HIP_MEMORY_SCOPE_AGENT);
        if (__all((int)(vfl >= (unsigned)t))) break;
        __builtin_amdgcn_s_sleep(1);
      }
    }
    __syncthreads();  // gates h restage; all waves done reading x from hl4
    // ---- phase H: stage h slot t, accumulate W_hh @ h ----
    {
      const uint4* s4 = reinterpret_cast<const uint4*>(hring + (size_t)t * HSLOT);
      uint4 v0 = s4[tid], v1 = s4[tid + 1024], v2 = s4[tid + 2048], v3 = s4[tid + 3072];
      int c0 = tid, c1 = tid + 1024, c2 = tid + 2048, c3 = tid + 3072;
      hl4[(c0 >> 7) * 128 + ((c0 & 127) ^ ((c0 >> 7) & 7))] = v0;
      hl4[(c1 >> 7) * 128 + ((c1 & 127) ^ ((c1 >> 7) & 7))] = v1;
      hl4[(c2 >> 7) * 128 + ((c2 & 127) ^ ((c2 >> 7) & 7))] = v2;
      hl4[(c3 >> 7) * 128 + ((c3 & 127) ^ ((c3 >> 7) & 7))] = v3;
    }
    __syncthreads();
#pragma unroll
    for (int kk = 0; kk < 8; ++kk) {
      int c16 = cb + kk * 4;
      bf16x8 b0 = *reinterpret_cast<const bf16x8*>(&hl4[r * 128 + (c16 ^ (r & 7))]);
      bf16x8 b1 = *reinterpret_cast<const bf16x8*>(&hl4[(r + 16) * 128 + (c16 ^ (r & 7))]);
      acc0 = __builtin_amdgcn_mfma_f32_16x16x32_bf16(ah[kk], b0, acc0, 0, 0, 0);
      acc1 = __builtin_amdgcn_mfma_f32_16x16x32_bf16(ah[kk], b1, acc1, 0, 0, 0);
    }
#pragma unroll
    for (int e = 0; e < 4; ++e) {
      red[q][ks][g * 4 + e][r] = acc0[e];
      red[q][ks][g * 4 + e][r + 16] = acc1[e];
    }
    __syncthreads();
    if (tid < 512) {
      float ig = red[qq][0][0 + hl][eb]  + red[qq][1][0 + hl][eb]  + red[qq][2][0 + hl][eb]  + red[qq][3][0 + hl][eb]  + bs_i;
      float fg = red[qq][0][4 + hl][eb]  + red[qq][1][4 + hl][eb]  + red[qq][2][4 + hl][eb]  + red[qq][3][4 + hl][eb]  + bs_f;
      float gg = red[qq][0][8 + hl][eb]  + red[qq][1][8 + hl][eb]  + red[qq][2][8 + hl][eb]  + red[qq][3][8 + hl][eb]  + bs_g;
      float og = red[qq][0][12 + hl][eb] + red[qq][1][12 + hl][eb] + red[qq][2][12 + hl][eb] + red[qq][3][12 + hl][eb] + bs_o;
      float si = 1.f / (1.f + __expf(-ig));
      float sf = 1.f / (1.f + __expf(-fg));
      float so = 1.f / (1.f + __expf(-og));
      float c_new = sf * c_reg + si * tanhf(gg);
      float h_new = so * tanhf(c_new);
      c_reg = c_new;
      hs[eb][qq * 4 + hl] = f2b(h_new);
      if (t == T_ - 1) {
        out[OUT_H + eb * 1024 + ehidx] = h_new;
        out[OUT_CC + eb * 1024 + ehidx] = c_new;
      }
    }
    __syncthreads();  // hs ready
    if (t != T_ - 1 && w == 0) {
      // publish h slice via agent-scope (coherence-point) dword stores + monotonic flag
      ushort* hout = hring + (size_t)(t + 1) * HSLOT;
      int b = lane >> 1, half = lane & 1;
      uint4 vv = *reinterpret_cast<const uint4*>(&hs[b][half * 8]);
      unsigned* hp = reinterpret_cast<unsigned*>(hout) + b * 512 + wg * 8 + half * 4;
      __hip_atomic_store(hp + 0, vv.x, __ATOMIC_RELAXED, __HIP_MEMORY_SCOPE_AGENT);
      __hip_atomic_store(hp + 1, vv.y, __ATOMIC_RELAXED, __HIP_MEMORY_SCOPE_AGENT);
      __hip_atomic_store(hp + 2, vv.z, __ATOMIC_RELAXED, __HIP_MEMORY_SCOPE_AGENT);
      __hip_atomic_store(hp + 3, vv.w, __ATOMIC_RELAXED, __HIP_MEMORY_SCOPE_AGENT);
      asm volatile("s_waitcnt vmcnt(0)" ::: "memory");
      if (lane == 0)
        __hip_atomic_store(&flags[wg * 16], (unsigned)(t + 1), __ATOMIC_RELAXED, __HIP_MEMORY_SCOPE_AGENT);
    }
  }
}

extern "C" void kernel_launch(void* const* d_in, const int* in_sizes, int n_in,
                              void* d_out, int out_size, void* d_ws, size_t ws_size,
                              hipStream_t stream) {
  const float* inp = (const float*)d_in[0];
  const float* ctx = (const float*)d_in[1];
  const float* Wih = (const float*)d_in[2];
  const float* Whh = (const float*)d_in[3];
  const float* bih = (const float*)d_in[4];
  const float* bhh = (const float*)d_in[5];
  const float* W1  = (const float*)d_in[6];
  const float* W2  = (const float*)d_in[8];
  float* out = (float*)d_out;
  char* wsb = (char*)d_ws;

  float* v     = (float*)(wsb + 0);          // 4 KB
  float* bias  = (float*)(wsb + 4096);       // 16 KB
  ushort* hring = (ushort*)(wsb + 32768);    // 33 slots x 64 KB = 2112 KB
  ushort* inpb = (ushort*)(wsb + 2195456);   // 2 MB
  unsigned* flags = (unsigned*)(wsb + 4292608); // 4 KB (64 flags, 64B apart)

  hipLaunchKernelGGL(k_init, dim3(537), dim3(256), 0, stream,
                     inp, inpb, W1, W2, bih, bhh, v, bias, hring, flags);

  const float* Whh_c = Whh;
  const float* Wih_c = Wih;
  const ushort* inpb_c = inpb;
  const float* ctx_c = ctx;
  const float* v_c = v;
  const float* bias_c = bias;
  void* kargs[9];
  kargs[0] = (void*)&Whh_c;
  kargs[1] = (void*)&Wih_c;
  kargs[2] = (void*)&inpb_c;
  kargs[3] = (void*)&hring;
  kargs[4] = (void*)&ctx_c;
  kargs[5] = (void*)&v_c;
  kargs[6] = (void*)&bias_c;
  kargs[7] = (void*)&out;
  kargs[8] = (void*)&flags;
  hipLaunchCooperativeKernel((const void*)k_rec, dim3(NWG + 32), dim3(1024), kargs, 0, stream);
}

// Round 24
// 199.110 us; speedup vs baseline: 1.4971x; 1.0711x over previous
//
#include <hip/hip_runtime.h>

#define T_ 32
#define B_ 32
#define S_ 64
#define C_ 1024
#define H_ 1024
#define NWG 64
#define HSLOT 32768  // ushorts per h ring slot / per x_t slab (32 x 1024)

typedef __attribute__((ext_vector_type(8))) short bf16x8;
typedef __attribute__((ext_vector_type(4))) float f32x4;

// d_out layout (float offsets): outputs[32*32*1024], h[32*1024], c[32*1024], attn[32*32*64]
#define OUT_H   1048576
#define OUT_CC  1081344
#define OUT_AT  1114112

__device__ __forceinline__ ushort f2b(float f) {
  unsigned u = __float_as_uint(f);
  unsigned r = (u + 0x7FFFu + ((u >> 16) & 1u)) >> 16;
  return (ushort)r;
}
__device__ __forceinline__ float b2f(ushort h) {
  return __uint_as_float(((unsigned)h) << 16);
}

// ---------------- init: cvt inp/Wih/Whh to bf16, v = W2@W1_x, bias, zero h slot0, zero flags ----------------
__global__ __launch_bounds__(256) void k_init(const float* __restrict__ inp, ushort* __restrict__ inpb,
                                              const float* __restrict__ Wih, ushort* __restrict__ Wihb,
                                              const float* __restrict__ Whh, ushort* __restrict__ Whhb,
                                              const float* __restrict__ W1, const float* __restrict__ W2,
                                              const float* __restrict__ bih, const float* __restrict__ bhh,
                                              float* __restrict__ v, float* __restrict__ bias,
                                              ushort* __restrict__ hring, unsigned* __restrict__ flags) {
  int blk = blockIdx.x, tid = threadIdx.x;
  if (blk < 4608) {
    const float* src; ushort* dst; int base;
    if (blk < 512) { src = inp; dst = inpb; base = blk; }
    else if (blk < 2560) { src = Wih; dst = Wihb; base = blk - 512; }
    else { src = Whh; dst = Whhb; base = blk - 2560; }
    size_t i = ((size_t)base * 256 + tid) * 8;
    float4 v0 = *reinterpret_cast<const float4*>(src + i);
    float4 v1 = *reinterpret_cast<const float4*>(src + i + 4);
    uint4 o;
    o.x = (unsigned)f2b(v0.x) | ((unsigned)f2b(v0.y) << 16);
    o.y = (unsigned)f2b(v0.z) | ((unsigned)f2b(v0.w) << 16);
    o.z = (unsigned)f2b(v1.x) | ((unsigned)f2b(v1.y) << 16);
    o.w = (unsigned)f2b(v1.z) | ((unsigned)f2b(v1.w) << 16);
    *reinterpret_cast<uint4*>(dst + i) = o;
  } else if (blk < 4612) {
    int c = (blk - 4608) * 256 + tid;
    float acc = 0.f;
#pragma unroll 8
    for (int a = 0; a < 128; ++a) acc += W1[a * 2048 + 1024 + c] * W2[a];
    v[c] = acc;
  } else if (blk < 4628) {
    int jj = (blk - 4612) * 256 + tid;
    bias[jj] = bih[jj] + bhh[jj];
  } else if (blk < 4632) {
    unsigned* hz = reinterpret_cast<unsigned*>(hring);
    int base = (blk - 4628) * 4096;
    for (int i = 0; i < 16; ++i) hz[base + i * 256 + tid] = 0u;
  } else {
    for (int i = 0; i < 4; ++i) flags[i * 256 + tid] = 0u;
  }
}

// ---------------- cooperative kernel: 96 WGs x 1024 threads ----------------
// WGs 0..63: persistent recurrence + fused x-projection (r11 structure, measured 5.25 us/step).
// WGs 64..95: attention (time-invariant) + outputs/attn broadcast on otherwise-idle CUs; exit.
__global__ __launch_bounds__(1024, 4) void k_rec(const ushort* __restrict__ Whhb, const ushort* __restrict__ Wihb,
                                                 const ushort* __restrict__ inpb, ushort* __restrict__ hring,
                                                 const float* __restrict__ ctx, const float* __restrict__ v,
                                                 const float* __restrict__ bias,
                                                 float* __restrict__ out, unsigned* __restrict__ flags) {
  int tid = threadIdx.x, lane = tid & 63, w = tid >> 6;
  int wg = blockIdx.x;

  __shared__ uint4 hl4[4096];           // 64 KB staging (x_t, then h): idx = row*128 + (c16 ^ (row&7))
  __shared__ float red[4][4][16][32];   // 32 KB K-slice partials
  __shared__ __align__(16) ushort hs[32][16];
  __shared__ float v_s[1024];           // attention path
  __shared__ float sc_s[64];
  __shared__ float att_s[64];

  if (wg >= NWG) {
    // ================= attention path (1 batch per WG; barriers hit by all 1024 threads) =================
    int b = wg - NWG;
    v_s[tid] = v[tid];
    __syncthreads();
    {
      int s = w * 4;
#pragma unroll
      for (int si = 0; si < 4; ++si, ++s) {
        const float* xr = ctx + (size_t)(s * B_ + b) * C_;
        float acc = 0.f;
#pragma unroll
        for (int i = 0; i < 16; ++i) { int c = lane + i * 64; acc += xr[c] * v_s[c]; }
        for (int off = 32; off; off >>= 1) acc += __shfl_down(acc, off);
        if (lane == 0) sc_s[s] = acc;
      }
    }
    __syncthreads();
    if (tid < 64) {
      float val = sc_s[tid];
      float mx = val;
      for (int off = 32; off; off >>= 1) mx = fmaxf(mx, __shfl_xor(mx, off));
      float e = expf(val - mx);
      float sm = e;
      for (int off = 32; off; off >>= 1) sm += __shfl_xor(sm, off);
      att_s[tid] = e / sm;
    }
    __syncthreads();
    if (tid < 256) {
      const float4* ctx4 = reinterpret_cast<const float4*>(ctx);
      float4 a4 = {0.f, 0.f, 0.f, 0.f};
      for (int s = 0; s < 64; ++s) {
        float a = att_s[s];
        float4 x = ctx4[(size_t)(s * B_ + b) * 256 + tid];
        a4.x += a * x.x; a4.y += a * x.y; a4.z += a * x.z; a4.w += a * x.w;
      }
#pragma unroll 4
      for (int t = 0; t < T_; ++t)
        reinterpret_cast<float4*>(out + (size_t)(t * B_ + b) * C_)[tid] = a4;
    }
    if (tid < 64) {
      float av = att_s[tid];
#pragma unroll 4
      for (int t = 0; t < T_; ++t) out[OUT_AT + (t * B_ + b) * 64 + tid] = av;
    }
    return;
  }

  // ================= recurrence path (r11 structure) =================
  int q = w & 3, ks = w >> 2;
  int g = lane >> 4, r = lane & 15;
  int hidx0 = wg * 16 + q * 4;
  int kbase = ks * 256;
  int j = (r >> 2) * 1024 + hidx0 + (r & 3);
  bf16x8 ah[8], ax[8];
  {
    const ushort* ap = Whhb + (size_t)j * 1024 + kbase + g * 8;
    const ushort* axp = Wihb + (size_t)j * 1024 + kbase + g * 8;
#pragma unroll
    for (int kk = 0; kk < 8; ++kk) {
      ah[kk] = *reinterpret_cast<const bf16x8*>(ap + kk * 32);
      ax[kk] = *reinterpret_cast<const bf16x8*>(axp + kk * 32);
    }
  }
  float c_reg = 0.f;
  int eb = tid & 31, hl = (tid >> 5) & 3, qq = tid >> 7;  // epilogue cell (tid<512)
  int ehidx = wg * 16 + qq * 4 + hl;
  float bs_i = 0.f, bs_f = 0.f, bs_g = 0.f, bs_o = 0.f;
  if (tid < 512) {
    bs_i = bias[ehidx];
    bs_f = bias[1024 + ehidx];
    bs_g = bias[2048 + ehidx];
    bs_o = bias[3072 + ehidx];
  }
  int cb = ks * 32 + g;

#pragma unroll 1
  for (int t = 0; t < T_; ++t) {
    // ---- phase X: stage x_t (no dependency) and accumulate W_ih @ x_t ----
    {
      const uint4* s4 = reinterpret_cast<const uint4*>(inpb + (size_t)t * HSLOT);
      uint4 v0 = s4[tid], v1 = s4[tid + 1024], v2 = s4[tid + 2048], v3 = s4[tid + 3072];
      int c0 = tid, c1 = tid + 1024, c2 = tid + 2048, c3 = tid + 3072;
      hl4[(c0 >> 7) * 128 + ((c0 & 127) ^ ((c0 >> 7) & 7))] = v0;
      hl4[(c1 >> 7) * 128 + ((c1 & 127) ^ ((c1 >> 7) & 7))] = v1;
      hl4[(c2 >> 7) * 128 + ((c2 & 127) ^ ((c2 >> 7) & 7))] = v2;
      hl4[(c3 >> 7) * 128 + ((c3 & 127) ^ ((c3 >> 7) & 7))] = v3;
    }
    __syncthreads();
    f32x4 acc0 = (f32x4)(0.f), acc1 = (f32x4)(0.f);
#pragma unroll
    for (int kk = 0; kk < 8; ++kk) {
      int c16 = cb + kk * 4;
      bf16x8 b0 = *reinterpret_cast<const bf16x8*>(&hl4[r * 128 + (c16 ^ (r & 7))]);
      bf16x8 b1 = *reinterpret_cast<const bf16x8*>(&hl4[(r + 16) * 128 + (c16 ^ (r & 7))]);
      acc0 = __builtin_amdgcn_mfma_f32_16x16x32_bf16(ax[kk], b0, acc0, 0, 0, 0);
      acc1 = __builtin_amdgcn_mfma_f32_16x16x32_bf16(ax[kk], b1, acc1, 0, 0, 0);
    }
    // ---- poll: single wave, all 64 producer flags, one 64-lane bypass load ----
    if (t > 0 && w == 0) {
      for (;;) {
        unsigned vfl = __hip_atomic_load(&flags[lane * 16], __ATOMIC_RELAXED, __HIP_MEMORY_SCOPE_AGENT);
        if (__all((int)(vfl >= (unsigned)t))) break;
        __builtin_amdgcn_s_sleep(1);
      }
    }
    __syncthreads();  // gates h restage; all waves done reading x from hl4
    // ---- phase H: stage h slot t, accumulate W_hh @ h ----
    {
      const uint4* s4 = reinterpret_cast<const uint4*>(hring + (size_t)t * HSLOT);
      uint4 v0 = s4[tid], v1 = s4[tid + 1024], v2 = s4[tid + 2048], v3 = s4[tid + 3072];
      int c0 = tid, c1 = tid + 1024, c2 = tid + 2048, c3 = tid + 3072;
      hl4[(c0 >> 7) * 128 + ((c0 & 127) ^ ((c0 >> 7) & 7))] = v0;
      hl4[(c1 >> 7) * 128 + ((c1 & 127) ^ ((c1 >> 7) & 7))] = v1;
      hl4[(c2 >> 7) * 128 + ((c2 & 127) ^ ((c2 >> 7) & 7))] = v2;
      hl4[(c3 >> 7) * 128 + ((c3 & 127) ^ ((c3 >> 7) & 7))] = v3;
    }
    __syncthreads();
#pragma unroll
    for (int kk = 0; kk < 8; ++kk) {
      int c16 = cb + kk * 4;
      bf16x8 b0 = *reinterpret_cast<const bf16x8*>(&hl4[r * 128 + (c16 ^ (r & 7))]);
      bf16x8 b1 = *reinterpret_cast<const bf16x8*>(&hl4[(r + 16) * 128 + (c16 ^ (r & 7))]);
      acc0 = __builtin_amdgcn_mfma_f32_16x16x32_bf16(ah[kk], b0, acc0, 0, 0, 0);
      acc1 = __builtin_amdgcn_mfma_f32_16x16x32_bf16(ah[kk], b1, acc1, 0, 0, 0);
    }
#pragma unroll
    for (int e = 0; e < 4; ++e) {
      red[q][ks][g * 4 + e][r] = acc0[e];
      red[q][ks][g * 4 + e][r + 16] = acc1[e];
    }
    __syncthreads();
    if (tid < 512) {
      float ig = red[qq][0][0 + hl][eb]  + red[qq][1][0 + hl][eb]  + red[qq][2][0 + hl][eb]  + red[qq][3][0 + hl][eb]  + bs_i;
      float fg = red[qq][0][4 + hl][eb]  + red[qq][1][4 + hl][eb]  + red[qq][2][4 + hl][eb]  + red[qq][3][4 + hl][eb]  + bs_f;
      float gg = red[qq][0][8 + hl][eb]  + red[qq][1][8 + hl][eb]  + red[qq][2][8 + hl][eb]  + red[qq][3][8 + hl][eb]  + bs_g;
      float og = red[qq][0][12 + hl][eb] + red[qq][1][12 + hl][eb] + red[qq][2][12 + hl][eb] + red[qq][3][12 + hl][eb] + bs_o;
      float si = 1.f / (1.f + __expf(-ig));
      float sf = 1.f / (1.f + __expf(-fg));
      float so = 1.f / (1.f + __expf(-og));
      float c_new = sf * c_reg + si * tanhf(gg);
      float h_new = so * tanhf(c_new);
      c_reg = c_new;
      hs[eb][qq * 4 + hl] = f2b(h_new);
      if (t == T_ - 1) {
        out[OUT_H + eb * 1024 + ehidx] = h_new;
        out[OUT_CC + eb * 1024 + ehidx] = c_new;
      }
    }
    __syncthreads();  // hs ready
    if (t != T_ - 1 && w == 0) {
      // publish h slice via agent-scope (coherence-point) dword stores + monotonic flag
      ushort* hout = hring + (size_t)(t + 1) * HSLOT;
      int b = lane >> 1, half = lane & 1;
      uint4 vv = *reinterpret_cast<const uint4*>(&hs[b][half * 8]);
      unsigned* hp = reinterpret_cast<unsigned*>(hout) + b * 512 + wg * 8 + half * 4;
      __hip_atomic_store(hp + 0, vv.x, __ATOMIC_RELAXED, __HIP_MEMORY_SCOPE_AGENT);
      __hip_atomic_store(hp + 1, vv.y, __ATOMIC_RELAXED, __HIP_MEMORY_SCOPE_AGENT);
      __hip_atomic_store(hp + 2, vv.z, __ATOMIC_RELAXED, __HIP_MEMORY_SCOPE_AGENT);
      __hip_atomic_store(hp + 3, vv.w, __ATOMIC_RELAXED, __HIP_MEMORY_SCOPE_AGENT);
      asm volatile("s_waitcnt vmcnt(0)" ::: "memory");
      if (lane == 0)
        __hip_atomic_store(&flags[wg * 16], (unsigned)(t + 1), __ATOMIC_RELAXED, __HIP_MEMORY_SCOPE_AGENT);
    }
  }
}

extern "C" void kernel_launch(void* const* d_in, const int* in_sizes, int n_in,
                              void* d_out, int out_size, void* d_ws, size_t ws_size,
                              hipStream_t stream) {
  const float* inp = (const float*)d_in[0];
  const float* ctx = (const float*)d_in[1];
  const float* Wih = (const float*)d_in[2];
  const float* Whh = (const float*)d_in[3];
  const float* bih = (const float*)d_in[4];
  const float* bhh = (const float*)d_in[5];
  const float* W1  = (const float*)d_in[6];
  const float* W2  = (const float*)d_in[8];
  float* out = (float*)d_out;
  char* wsb = (char*)d_ws;

  float* v     = (float*)(wsb + 0);          // 4 KB
  float* bias  = (float*)(wsb + 4096);       // 16 KB
  ushort* hring = (ushort*)(wsb + 32768);    // 33 slots x 64 KB = 2112 KB
  ushort* inpb = (ushort*)(wsb + 2195456);   // 2 MB
  ushort* Wihb = (ushort*)(wsb + 4292608);   // 8 MB
  ushort* Whhb = (ushort*)(wsb + 12681216);  // 8 MB
  unsigned* flags = (unsigned*)(wsb + 21069824); // 4 KB (64 flags, 64B apart)

  hipLaunchKernelGGL(k_init, dim3(4633), dim3(256), 0, stream,
                     inp, inpb, Wih, Wihb, Whh, Whhb, W1, W2, bih, bhh, v, bias, hring, flags);

  const ushort* Whhb_c = Whhb;
  const ushort* Wihb_c = Wihb;
  const ushort* inpb_c = inpb;
  const float* ctx_c = ctx;
  const float* v_c = v;
  const float* bias_c = bias;
  void* kargs[9];
  kargs[0] = (void*)&Whhb_c;
  kargs[1] = (void*)&Wihb_c;
  kargs[2] = (void*)&inpb_c;
  kargs[3] = (void*)&hring;
  kargs[4] = (void*)&ctx_c;
  kargs[5] = (void*)&v_c;
  kargs[6] = (void*)&bias_c;
  kargs[7] = (void*)&out;
  kargs[8] = (void*)&flags;
  hipLaunchCooperativeKernel((const void*)k_rec, dim3(NWG + 32), dim3(1024), kargs, 0, stream);
}